// Round 1
// 392.905 us; speedup vs baseline: 1.0475x; 1.0475x over previous
//
#include <hip/hip_runtime.h>
#include <math.h>

// Problem constants (setup_inputs: h,c,i,kk = 8,64,96,3; c2,n,d = 32,8,512)
#define H    8
#define N    8
#define D    512
#define C    64
#define C2   32
#define I    96        // spatial size (kk=3 is the conv kernel)
#define II   9216      // 96*96

// d_out flat layout (return order T, M, P, w), f32:
// T (8,64,96,96)=4718592 | M (8,8,32,1,1)=2048 | P (8,8,64,96,96)=37748736 | w same
#define OFF_T 0
#define OFF_M 4718592
#define OFF_P 4720640
#define OFF_W 42469376

// ws layout (floats). Factored forms:
//   kp[n,h,d,a,b] = A_k[n,h,d] + B_k[h,b,d](px-part) + C_k[h,a,d](py-part)
//   s*24 - sb[e]  = F[n][ra*3+rb][h][e] + G2[ra][h][e][b] + H2[rb][h][e][a]
// BkT2/CkT2 are zero-padded transposes: [h][d][100], col j=1..96 holds spatial j-1,
// cols {0,97,98,99} = 0 so the 3-tap window needs no boundary branches.
#define WS_AK    0        // [n][h][d]      4096
#define WS_AV    4096     // [n][h][d]      4096
#define WS_BV    8192     // [h][e][b]      49152   (b contiguous)
#define WS_CVT   57344    // [h][e][a]      49152   (a contiguous)
#define WS_BKT2  106496   // [h][d][100]    51200
#define WS_CKT2  157696   // [h][d][100]    51200
#define WS_SST   208896   // [cls][d][e]    36864   (cls = ra*3+rb, e contiguous)
#define WS_SPT   245760   // [ra*3+q][d][e] 36864
#define WS_SQT   282624   // [rb*3+p][d][e] 36864
#define WS_F     319488   // [n][cls][h][e] 36864
#define WS_G2    356352   // [ra][h][e][b]  147456  (b contiguous)
#define WS_H2    503808   // [rb][h][e][a]  147456  (a contiguous) -- LAYOUT CHANGED
// total 651264 floats = 2.49 MiB

__device__ __forceinline__ int bcls(int x) { return x == 0 ? 0 : (x == I - 1 ? 2 : 1); }

// ---------------- K1: per-head Linear -> BN(train) -> ReLU -> M -------------
__global__ __launch_bounds__(256) void irf_embed(
    const float* __restrict__ X, const float* __restrict__ lin_w,
    const float* __restrict__ lin_b, const float* __restrict__ gamma,
    const float* __restrict__ beta, float* __restrict__ out)
{
    const int h = blockIdx.x, t = threadIdx.x;
    const int n = t >> 5, cc = t & 31;

    __shared__ float Xs[N * D];
    __shared__ float ys[N * C2];
    __shared__ float scale_s[C2], shift_s[C2];

    const float4* Xg  = (const float4*)(X + (size_t)h * N * D);
    float4*       Xs4 = (float4*)Xs;
    for (int idx = t; idx < N * D / 4; idx += 256) Xs4[idx] = Xg[idx];
    __syncthreads();

    const float4* wrow = (const float4*)(lin_w + ((size_t)h * C2 + cc) * D);
    const float4* xrow = (const float4*)(Xs + n * D);
    float a0 = 0.f, a1 = 0.f, a2 = 0.f, a3 = 0.f;
    #pragma unroll 4
    for (int k = 0; k < D / 4; ++k) {
        float4 xv = xrow[k], wv = wrow[k];
        a0 = fmaf(xv.x, wv.x, a0); a1 = fmaf(xv.y, wv.y, a1);
        a2 = fmaf(xv.z, wv.z, a2); a3 = fmaf(xv.w, wv.w, a3);
    }
    float y = (a0 + a1) + (a2 + a3) + lin_b[h * C2 + cc];
    ys[n * C2 + cc] = y;
    __syncthreads();

    if (t < C2) {  // biased var (jnp.var ddof=0), eps 1e-5
        float s = 0.f, ss = 0.f;
        #pragma unroll
        for (int j = 0; j < N; ++j) { float v = ys[j * C2 + t]; s += v; ss += v * v; }
        float mu  = s * (1.0f / N);
        float var = ss * (1.0f / N) - mu * mu;
        float sc  = rsqrtf(var + 1e-5f) * gamma[h * C2 + t];
        scale_s[t] = sc;
        shift_s[t] = beta[h * C2 + t] - mu * sc;
    }
    __syncthreads();

    float v = fmaxf(fmaf(y, scale_s[cc], shift_s[cc]), 0.0f);
    out[OFF_M + (n * H + h) * C2 + cc] = v;    // M (n,h,c2)
}

// ---------------- K2a: separable factors + transposed conv operands --------
__global__ __launch_bounds__(256) void irf_factors_a(
    const float* __restrict__ kw, const float* __restrict__ kb,
    const float* __restrict__ vw, const float* __restrict__ vb,
    const float* __restrict__ px, const float* __restrict__ py,
    const float* __restrict__ sw, const float* __restrict__ out,
    float* __restrict__ ws)
{
    int gid = blockIdx.x * 256 + threadIdx.x;   // 61440 total
    if (gid < 4096) {
        // A_k/A_v[n,h,d] = bias + sum_{c<32}(w[h,d,c]+w[h,d,32+c]) * M[n,h,c]
        int id = gid, d = id & 63, h = (id >> 6) & 7, n = id >> 9;
        const float* kwr = kw + ((size_t)h * C + d) * C;
        const float* vwr = vw + ((size_t)h * C + d) * C;
        const float* Mr  = out + OFF_M + (n * H + h) * C2;
        float ak = kb[h * C + d], av = vb[h * C + d];
        #pragma unroll 8
        for (int c = 0; c < C2; ++c) {
            float m = Mr[c];
            ak = fmaf(kwr[c] + kwr[C2 + c], m, ak);
            av = fmaf(vwr[c] + vwr[C2 + c], m, av);
        }
        ws[WS_AK + id] = ak;
        ws[WS_AV + id] = av;
    } else if (gid < 4096 + 49152) {
        // B_*[h,b,d] = sum_{c<32} w[h,d,c]*px[c,b]; C_*[h,a,d] with w[h,d,32+c]*py[c,a]
        int id = gid - 4096, d = id & 63, r = id >> 6, b = r % I, h = r / I;
        const float* kwr = kw + ((size_t)h * C + d) * C;
        const float* vwr = vw + ((size_t)h * C + d) * C;
        float bk = 0.f, bv = 0.f, ck = 0.f, cv = 0.f;
        #pragma unroll 8
        for (int c = 0; c < C2; ++c) {
            float pxv = px[c * I + b], pyv = py[c * I + b];
            bk = fmaf(kwr[c], pxv, bk);       bv = fmaf(vwr[c], pxv, bv);
            ck = fmaf(kwr[C2 + c], pyv, ck);  cv = fmaf(vwr[C2 + c], pyv, cv);
        }
        ws[WS_BKT2 + (h * C + d) * 100 + (b + 1)] = bk;  // padded transpose
        ws[WS_BV   + (h * C + d) * I   + b]       = bv;  // [h][e][b]
        ws[WS_CKT2 + (h * C + d) * 100 + (b + 1)] = ck;  // padded transpose
        ws[WS_CVT  + (h * C + d) * I   + b]       = cv;  // [h][e][a]
    } else if (gid < 4096 + 49152 + 4096) {
        // per (e,d): SST[cls][d][e], SPT[ra*3+q][d][e], SQT[rb*3+p][d][e]
        int id = gid - (4096 + 49152), d = id & 63, e = id >> 6;
        float k9[3][3];
        const float* swr = sw + (size_t)(e * C + d) * 9;
        #pragma unroll
        for (int p = 0; p < 3; ++p)
            #pragma unroll
            for (int q = 0; q < 3; ++q) k9[p][q] = swr[p * 3 + q];
        #pragma unroll
        for (int ra = 0; ra < 3; ++ra) {
            int pmin = (ra == 0) ? 1 : 0, pmax = (ra == 2) ? 1 : 2;
            #pragma unroll
            for (int q = 0; q < 3; ++q) {
                float sp = 0.f;
                for (int p = pmin; p <= pmax; ++p) sp += k9[p][q];
                ws[WS_SPT + ((ra * 3 + q) * C + d) * C + e] = sp;
            }
            #pragma unroll
            for (int rb = 0; rb < 3; ++rb) {
                int qmin = (rb == 0) ? 1 : 0, qmax = (rb == 2) ? 1 : 2;
                float ssv = 0.f;
                for (int p = pmin; p <= pmax; ++p)
                    for (int q = qmin; q <= qmax; ++q) ssv += k9[p][q];
                ws[WS_SST + ((ra * 3 + rb) * C + d) * C + e] = ssv;
            }
        }
        #pragma unroll
        for (int rb = 0; rb < 3; ++rb) {
            int qmin = (rb == 0) ? 1 : 0, qmax = (rb == 2) ? 1 : 2;
            #pragma unroll
            for (int p = 0; p < 3; ++p) {
                float sq = 0.f;
                for (int q = qmin; q <= qmax; ++q) sq += k9[p][q];
                ws[WS_SQT + ((rb * 3 + p) * C + d) * C + e] = sq;
            }
        }
    } else {
        // zero the pad columns {0,97,98,99} of BkT2/CkT2 (8h*64d*4col*2arr = 4096)
        int s = gid - (4096 + 49152 + 4096);
        int d = s & 63, h = (s >> 6) & 7, k = s >> 9;     // k 0..7
        int col = (k & 3) == 0 ? 0 : 96 + (k & 3);        // 0,97,98,99
        int base = (k >> 2) ? WS_CKT2 : WS_BKT2;
        ws[base + (h * C + d) * 100 + col] = 0.f;
    }
}

// ---------------- K2b: conv precontractions F, G2, H2 (coalesced) ----------
__global__ __launch_bounds__(256) void irf_factors_b(float* __restrict__ ws)
{
    int gid = blockIdx.x * 256 + threadIdx.x;   // 110592 total
    if (gid < 36864) {
        // F[n][cls][h][e] = sum_d A_k[n,h,d] * SST[cls,d,e]   (lanes = e, coalesced)
        int e = gid & 63, h = (gid >> 6) & 7, cls = (gid >> 9) % 9, n = gid / 4608;
        const float* ak  = ws + WS_AK + (n * H + h) * C;       // wave-uniform
        const float* sst = ws + WS_SST + cls * (C * C) + e;    // lane-contiguous
        float acc = 0.f;
        #pragma unroll 8
        for (int d = 0; d < C; ++d) acc = fmaf(ak[d], sst[d * C], acc);
        ws[WS_F + gid] = acc;
    } else if (gid < 73728) {
        // G2[ra][h][e][b..b+3] via shifted-window float4 dot over BkT2 rows
        int j = gid - 36864;
        int b4 = j % 24, e = (j / 24) & 63, h = (j / 1536) & 7, ra = j / 12288;
        const float* sp  = ws + WS_SPT + (ra * 3) * (C * C) + e;   // + q*4096 + d*64
        const float* row = ws + WS_BKT2 + h * (C * 100) + 4 * b4;  // + d*100
        float4 acc = make_float4(0.f, 0.f, 0.f, 0.f);
        #pragma unroll 4
        for (int d = 0; d < C; ++d) {
            float s0 = sp[d * C], s1 = sp[4096 + d * C], s2 = sp[8192 + d * C];
            float4 A = *(const float4*)(row + d * 100);
            float4 B = *(const float4*)(row + d * 100 + 4);
            acc.x = fmaf(s0, A.x, fmaf(s1, A.y, fmaf(s2, A.z, acc.x)));
            acc.y = fmaf(s0, A.y, fmaf(s1, A.z, fmaf(s2, A.w, acc.y)));
            acc.z = fmaf(s0, A.z, fmaf(s1, A.w, fmaf(s2, B.x, acc.z)));
            acc.w = fmaf(s0, A.w, fmaf(s1, B.x, fmaf(s2, B.y, acc.w)));
        }
        ((float4*)(ws + WS_G2 + ((ra * H + h) * C + e) * I))[b4] = acc;
    } else {
        // H2[rb][h][e][a..a+3] via shifted-window float4 dot over CkT2 rows
        int j = gid - 73728;
        int a4 = j % 24, e = (j / 24) & 63, h = (j / 1536) & 7, rb = j / 12288;
        const float* sq  = ws + WS_SQT + (rb * 3) * (C * C) + e;
        const float* row = ws + WS_CKT2 + h * (C * 100) + 4 * a4;
        float4 acc = make_float4(0.f, 0.f, 0.f, 0.f);
        #pragma unroll 4
        for (int d = 0; d < C; ++d) {
            float s0 = sq[d * C], s1 = sq[4096 + d * C], s2 = sq[8192 + d * C];
            float4 A = *(const float4*)(row + d * 100);
            float4 B = *(const float4*)(row + d * 100 + 4);
            acc.x = fmaf(s0, A.x, fmaf(s1, A.y, fmaf(s2, A.z, acc.x)));
            acc.y = fmaf(s0, A.y, fmaf(s1, A.z, fmaf(s2, A.w, acc.y)));
            acc.z = fmaf(s0, A.z, fmaf(s1, A.w, fmaf(s2, B.x, acc.z)));
            acc.w = fmaf(s0, A.w, fmaf(s1, B.x, fmaf(s2, B.y, acc.w)));
        }
        ((float4*)(ws + WS_H2 + ((rb * H + h) * C + e) * I))[a4] = acc;
    }
}

// ---------------- K3: softmax over h + w + T, plane-major stores ------------
// block = (n, e): writes 8 contiguous 36.9KB w planes + 1 T plane.
__global__ __launch_bounds__(256) void irf_softmax(
    const float* __restrict__ sb, const float* __restrict__ ws,
    float* __restrict__ out)
{
    const int bid = blockIdx.x;          // 0..511 = n*64 + e
    const int n = bid >> 6, e = bid & 63;
    const int t = threadIdx.x;

    __shared__ __align__(16) float G2s[3 * H * I];   // [ra][h][b]
    __shared__ __align__(16) float H2s[3 * H * I];   // [rb][h][a]
    __shared__ __align__(16) float BVs[H * I];       // [h][b]
    __shared__ float CVs[H * I];                     // [h][a]
    __shared__ float Fs[9 * H];                      // [cls][h]
    __shared__ float AVs[H];

    for (int o = t; o < 3 * H * I; o += 256) {
        int rh = o / I, sp = o - rh * I;             // rh = r*8+h, sp = spatial
        G2s[o] = ws[WS_G2 + (rh * C + e) * I + sp];
        H2s[o] = ws[WS_H2 + (rh * C + e) * I + sp];
    }
    for (int o = t; o < H * I; o += 256) {
        int h = o / I, sp = o - h * I;
        BVs[o] = ws[WS_BV  + (h * C + e) * I + sp];
        CVs[o] = ws[WS_CVT + (h * C + e) * I + sp];
    }
    if (t < 9 * H) Fs[t] = ws[WS_F + ((n * 9 + t / 8) * H + (t & 7)) * C + e];
    if (t < H)     AVs[t] = ws[WS_AV + (n * H + t) * C + e];
    const float sbv = sb[e];
    __syncthreads();

    const float inv24 = 1.0f / 24.0f;    // 1/sqrt(c*kk*kk) = 1/sqrt(576)
    float4* Tplane = (float4*)(out + OFF_T + (size_t)(n * C + e) * II);

    #pragma unroll
    for (int it = 0; it < 9; ++it) {
        int idx = it * 256 + t;          // 0..2303 = a*24 + b4
        int a = idx / 24, b4 = idx - a * 24;
        int ra = bcls(a);

        float4 sv[H];
        float4 mx = make_float4(-1e30f, -1e30f, -1e30f, -1e30f);
        #pragma unroll
        for (int h = 0; h < H; ++h) {
            float4 g2 = ((const float4*)(G2s + (ra * H + h) * I))[b4];
            float f1 = Fs[(ra * 3 + 1) * H + h] + H2s[(H + h) * I + a] + sbv;
            float fx = f1, fw = f1;
            if (b4 == 0)  fx = Fs[(ra * 3 + 0) * H + h] + H2s[h * I + a] + sbv;
            if (b4 == 23) fw = Fs[(ra * 3 + 2) * H + h] + H2s[(2 * H + h) * I + a] + sbv;
            float4 s;
            s.x = (fx + g2.x) * inv24;
            s.y = (f1 + g2.y) * inv24;
            s.z = (f1 + g2.z) * inv24;
            s.w = (fw + g2.w) * inv24;
            sv[h] = s;
            mx.x = fmaxf(mx.x, s.x); mx.y = fmaxf(mx.y, s.y);
            mx.z = fmaxf(mx.z, s.z); mx.w = fmaxf(mx.w, s.w);
        }
        float4 sum = make_float4(0.f, 0.f, 0.f, 0.f);
        #pragma unroll
        for (int h = 0; h < H; ++h) {
            sv[h].x = __expf(sv[h].x - mx.x); sum.x += sv[h].x;
            sv[h].y = __expf(sv[h].y - mx.y); sum.y += sv[h].y;
            sv[h].z = __expf(sv[h].z - mx.z); sum.z += sv[h].z;
            sv[h].w = __expf(sv[h].w - mx.w); sum.w += sv[h].w;
        }
        float4 rs;
        rs.x = 1.0f / sum.x; rs.y = 1.0f / sum.y;
        rs.z = 1.0f / sum.z; rs.w = 1.0f / sum.w;

        float4 T = make_float4(0.f, 0.f, 0.f, 0.f);
        #pragma unroll
        for (int h = 0; h < H; ++h) {
            float4 w;
            w.x = sv[h].x * rs.x; w.y = sv[h].y * rs.y;
            w.z = sv[h].z * rs.z; w.w = sv[h].w * rs.w;
            ((float4*)(out + OFF_W + (size_t)((n * H + h) * C + e) * II))[idx] = w;
            float ac = AVs[h] + CVs[h * I + a];
            float4 bv = ((const float4*)(BVs + h * I))[b4];
            T.x = fmaf(w.x, ac + bv.x, T.x);
            T.y = fmaf(w.y, ac + bv.y, T.y);
            T.z = fmaf(w.z, ac + bv.z, T.z);
            T.w = fmaf(w.w, ac + bv.w, T.w);
        }
        Tplane[idx] = T;
    }
}

// ---------------- K4: P planes, fully linear streaming writes ---------------
// block = (n,h,c): P[n,h,c,:,:] = c<32 ? M+px[c,b] (bcast over a) : M+py[c-32,a]
__global__ __launch_bounds__(256) void irf_pwrite(
    const float* __restrict__ px, const float* __restrict__ py,
    float* __restrict__ out)
{
    const int bid = blockIdx.x;          // 0..4095 = (n*8+h)*64 + c
    const int c = bid & 63, nh = bid >> 6;
    const int t = threadIdx.x;

    __shared__ __align__(16) float rowp[I];
    const float m = out[OFF_M + nh * C2 + (c & 31)];
    if (t < I / 4) {
        const float* src = (c < C2) ? (px + c * I) : (py + (c - C2) * I);
        ((float4*)rowp)[t] = ((const float4*)src)[t];
    }
    __syncthreads();

    float4* plane = (float4*)(out + OFF_P + (size_t)bid * II);
    if (c < C2) {
        #pragma unroll
        for (int it = 0; it < 9; ++it) {
            int idx = it * 256 + t;
            float4 v = ((const float4*)rowp)[idx % 24];
            v.x += m; v.y += m; v.z += m; v.w += m;
            plane[idx] = v;
        }
    } else {
        #pragma unroll
        for (int it = 0; it < 9; ++it) {
            int idx = it * 256 + t;
            float vv = m + rowp[idx / 24];
            plane[idx] = make_float4(vv, vv, vv, vv);
        }
    }
}

extern "C" void kernel_launch(void* const* d_in, const int* in_sizes, int n_in,
                              void* d_out, int out_size, void* d_ws, size_t ws_size,
                              hipStream_t stream) {
    const float* X     = (const float*)d_in[0];
    const float* lin_w = (const float*)d_in[1];
    const float* lin_b = (const float*)d_in[2];
    const float* gamma = (const float*)d_in[3];
    const float* beta  = (const float*)d_in[4];
    const float* px    = (const float*)d_in[5];
    const float* py    = (const float*)d_in[6];
    const float* kw    = (const float*)d_in[7];
    const float* kb    = (const float*)d_in[8];
    const float* vw    = (const float*)d_in[9];
    const float* vb    = (const float*)d_in[10];
    const float* sw    = (const float*)d_in[11];
    const float* sb    = (const float*)d_in[12];

    float* out = (float*)d_out;
    float* ws  = (float*)d_ws;     // needs 651264 floats = 2.49 MiB

    irf_embed    <<<8,    256, 0, stream>>>(X, lin_w, lin_b, gamma, beta, out);
    irf_factors_a<<<240,  256, 0, stream>>>(kw, kb, vw, vb, px, py, sw, out, ws);
    irf_factors_b<<<432,  256, 0, stream>>>(ws);
    irf_softmax  <<<512,  256, 0, stream>>>(sb, ws, out);
    irf_pwrite   <<<4096, 256, 0, stream>>>(px, py, out);
}